// Round 10
// baseline (365.943 us; speedup 1.0000x reference)
//
#include <hip/hip_runtime.h>
#include <hip/hip_bf16.h>
#include <cstdint>
#include <cstddef>

#define IC 512     // in_caps
#define IDM 768    // in_dim
#define KC 16      // num_caps
#define NB 128     // batch
#define NOUT 1024  // KC*DC

typedef __attribute__((ext_vector_type(8))) short short8v;
typedef __attribute__((ext_vector_type(4))) float f32x4;

#define MFMA __builtin_amdgcn_mfma_f32_16x16x32_bf16

static __device__ __forceinline__ unsigned fbits(float x) {
  union { float f; unsigned u; } z; z.f = x; return z.u;
}
static __device__ __forceinline__ float bf_f(ushort u) {
  union { float f; unsigned u32; } z; z.u32 = ((unsigned)u) << 16; return z.f;
}
static __device__ __forceinline__ ushort bf_rne(float x) {
  __hip_bfloat16 h = __float2bfloat16(x);
  return *reinterpret_cast<ushort*>(&h);
}
// truncation hi/lo split (GEMM input path only)
static __device__ __forceinline__ void split2(float x, ushort& h, ushort& l) {
  h = (ushort)(fbits(x) >> 16);
  const float r = x - bf_f(h);
  l = (ushort)(fbits(r) >> 16);
}
static __device__ __forceinline__ void split8(const float* p, short8v& h, short8v& l) {
  const float4 x0 = *(const float4*)p;
  const float4 x1 = *(const float4*)(p + 4);
  const float xs[8] = {x0.x, x0.y, x0.z, x0.w, x1.x, x1.y, x1.z, x1.w};
  #pragma unroll
  for (int j = 0; j < 8; ++j) {
    ushort hh, ll; split2(xs[j], hh, ll);
    h[j] = (short)hh; l[j] = (short)ll;
  }
}
static __device__ __forceinline__ float tanh_fast(float x) {
  const float e2 = __expf(2.0f * x);
  return 1.0f - 2.0f / (e2 + 1.0f);
}

struct KArgs {
  const float *m, *q, *Ww, *Wb;
  ushort *Hb, *HTb;        // hat_m bf16 [i][n] and [n][i]
  ushort *Yb0;             // y round-0 bf16 [b][1024]
  float *smT, *ixT;        // H row stats of bf16 values: [i][16] = sum/64, invnorm
  float *syT0, *invyT0;    // y round-0 stats: [k][b]
  float *outp;
};

// ===================== K1: GEMM (hi/lo f32-accurate) + bf16 epilogue ============
// identical to R9-verified kernel except stat layout: smT/ixT packed [i][16].
__global__ __launch_bounds__(256) void k_gemm(KArgs A)
{
  __shared__ float sred[2][2][32];
  const int t = threadIdx.x;
  const int bid = blockIdx.x;
  const int region = bid & 7, idx = bid >> 3;
  const int rt = (region & 1) * 10 + (idx % 10);
  const int nt = (region >> 1) * 4 + (idx / 10);
  const int w = t >> 6, L = t & 63, c = L & 15, g = L >> 4;
  const int wr = w >> 1, wc = w & 1;
  const int r0 = rt * 32, n0 = nt * 64;
  const int arow = r0 + wr * 16 + c;
  const int bcol = n0 + wc * 32 + c;
  const float* asrc = (arow < IC) ? (A.m + (size_t)arow * IDM)
                                  : (A.q + (size_t)(arow - IC) * IDM);
  const float* b0src = A.Ww + (size_t)bcol * IDM;
  const float* b1src = A.Ww + (size_t)(bcol + 16) * IDM;

  f32x4 acc0 = {}, acc1 = {};
  #pragma unroll 2
  for (int kb = 0; kb < IDM; kb += 32) {
    short8v ah, al, bh0, bl0, bh1, bl1;
    split8(asrc + kb + g * 8, ah, al);
    split8(b0src + kb + g * 8, bh0, bl0);
    split8(b1src + kb + g * 8, bh1, bl1);
    acc0 = MFMA(ah, bh0, acc0, 0, 0, 0);
    acc0 = MFMA(ah, bl0, acc0, 0, 0, 0);
    acc0 = MFMA(al, bh0, acc0, 0, 0, 0);
    acc1 = MFMA(ah, bh1, acc1, 0, 0, 0);
    acc1 = MFMA(ah, bl1, acc1, 0, 0, 0);
    acc1 = MFMA(al, bh1, acc1, 0, 0, 0);
  }

  const float bias0 = A.Wb[bcol];
  const float bias1 = A.Wb[bcol + 16];
  ushort h0[4], h1[4];
  float r0s[4], r1s[4];
  #pragma unroll
  for (int j = 0; j < 4; ++j) {
    h0[j] = bf_rne(acc0[j] + bias0); r0s[j] = bf_f(h0[j]);
    h1[j] = bf_rne(acc1[j] + bias1); r1s[j] = bf_f(h1[j]);
  }

  #pragma unroll
  for (int j = 0; j < 4; ++j) {
    float s = r0s[j] + r1s[j];
    float q2 = r0s[j] * r0s[j] + r1s[j] * r1s[j];
    #pragma unroll
    for (int off = 1; off < 16; off <<= 1) {
      s += __shfl_xor(s, off);
      q2 += __shfl_xor(q2, off);
    }
    if (c == 0) {
      sred[wc][0][wr * 16 + 4 * g + j] = s;
      sred[wc][1][wr * 16 + 4 * g + j] = q2;
    }
  }

  const int rowb = r0 + wr * 16 + 4 * g;
  if (rowb < IC) {
    #pragma unroll
    for (int j = 0; j < 4; ++j) {
      const size_t r = (size_t)(rowb + j) * NOUT;
      A.Hb[r + bcol] = h0[j];
      A.Hb[r + bcol + 16] = h1[j];
    }
    *(ushort4*)&A.HTb[(size_t)bcol * 512 + rowb] = make_ushort4(h0[0], h0[1], h0[2], h0[3]);
    *(ushort4*)&A.HTb[(size_t)(bcol + 16) * 512 + rowb] = make_ushort4(h1[0], h1[1], h1[2], h1[3]);
  } else {
    #pragma unroll
    for (int j = 0; j < 4; ++j) {
      const size_t r = (size_t)(rowb + j - IC) * NOUT;
      A.Yb0[r + bcol] = h0[j];
      A.Yb0[r + bcol + 16] = h1[j];
    }
  }
  __syncthreads();
  if (t < 32) {
    const int row = r0 + t;
    const float s = sred[0][0][t] + sred[1][0][t];
    const float q2 = sred[0][1][t] + sred[1][1][t];
    const float inv = rsqrtf(q2 - s * s * (1.0f / 64.0f));
    if (row < IC) {
      A.smT[row * 16 + nt] = s * (1.0f / 64.0f);
      A.ixT[row * 16 + nt] = inv;
    } else {
      A.syT0[nt * 128 + (row - IC)] = s;
      A.invyT0[nt * 128 + (row - IC)] = inv;
    }
  }
}

// ===================== K2: full 3-round routing, one block = 4 b's ==============
// 32 blocks x 512 thr (8 waves). All state for the block's b's in LDS; rounds
// separated only by __syncthreads. No cross-block dependencies.
__global__ __launch_bounds__(512) void k_route(KArgs A)
{
  __shared__ ushort D[4][8200];     // dsp bf16 [b][k*512 + i] (+8 pad/plane)
  __shared__ ushort yL[4][1040];    // y bf16 [b][k*64+d]
  __shared__ ushort vL[4][1040];    // vsum bf16
  __shared__ float syL[4][16], iyL[4][16];

  const int t = threadIdx.x;
  const int b0 = blockIdx.x * 4;
  const int w = t >> 6, L = t & 63, c = L & 15, g = L >> 4;
  const int b_t = L >> 4, il = L & 15;   // softmax-lane mapping (b_t==g)

  // ---- init: y0 from GEMM, vsum = 0, round-0 y stats ----
  {
    const int flat = t * 8;              // 4096 bf16 total
    const int r = flat >> 10, ci = flat & 1023;
    *(short8v*)&yL[r][ci] =
        *(const short8v*)&A.Yb0[(size_t)(b0 + r) * 1024 + ci];
    short8v z = {};
    *(short8v*)&vL[r][ci] = z;
  }
  if (t < 64) {
    syL[t >> 4][t & 15] = A.syT0[(size_t)(t & 15) * 128 + b0 + (t >> 4)];
    iyL[t >> 4][t & 15] = A.invyT0[(size_t)(t & 15) * 128 + b0 + (t >> 4)];
  }
  __syncthreads();

  for (int round = 0; round < 3; ++round) {
    // ===== phase 1: corr (P,a packed in one MFMA) + softmax + D =====
    // wave w owns i-tiles 4w..4w+3; B cols: 0-3 = y[b], 4-7 = vsum[b], 8-15 = 0
    for (int n = 0; n < 4; ++n) {
      const int i0 = (w * 4 + n) * 16;
      f32x4 acc[16];
      #pragma unroll
      for (int k = 0; k < 16; ++k) acc[k] = f32x4{0.f, 0.f, 0.f, 0.f};
      #pragma unroll 4
      for (int k = 0; k < 16; ++k) {
        #pragma unroll
        for (int ks = 0; ks < 2; ++ks) {
          short8v Bf = {};
          if (c < 4)      Bf = *(const short8v*)&yL[c][k * 64 + ks * 32 + g * 8];
          else if (c < 8) Bf = *(const short8v*)&vL[c - 4][k * 64 + ks * 32 + g * 8];
          const short8v Af = *(const short8v*)
              &A.Hb[(size_t)(i0 + c) * 1024 + k * 64 + ks * 32 + g * 8];
          acc[k] = MFMA(Af, Bf, acc[k], 0, 0, 0);
        }
      }
      // redistribute: target lane (b_t, il) gathers P from col b_t, a from col b_t+4,
      // source lane = (il>>2)*16 + col, element j = il&3  (C: col=lane&15, row=4g+j)
      const int srcP = (il >> 2) * 16 + b_t;
      const int srcA = srcP + 4;
      const int jsel = il & 3;
      float p[16], a[16];
      #pragma unroll
      for (int k = 0; k < 16; ++k) {
        float pv = 0.f, av = 0.f;
        #pragma unroll
        for (int j = 0; j < 4; ++j) {
          const float tp = __shfl(acc[k][j], srcP, 64);
          const float ta = __shfl(acc[k][j], srcA, 64);
          if (jsel == j) { pv = tp; av = ta; }
        }
        p[k] = pv; a[k] = av;
      }
      const int i = i0 + il;
      f32x4 sm4[4], ix4[4];
      #pragma unroll
      for (int mm = 0; mm < 4; ++mm) {
        sm4[mm] = *(const f32x4*)&A.smT[(size_t)i * 16 + mm * 4];
        ix4[mm] = *(const f32x4*)&A.ixT[(size_t)i * 16 + mm * 4];
      }
      // softmax over a (round 0: vsum=0 -> a=0 -> d = 1/16 exactly)
      float mx = -1e30f;
      #pragma unroll
      for (int k = 0; k < 16; ++k) mx = fmaxf(mx, a[k]);
      float ev[16];
      float es = 0.f;
      #pragma unroll
      for (int k = 0; k < 16; ++k) { ev[k] = __expf(a[k] - mx); es += ev[k]; }
      const float inv = 1.0f / es;
      #pragma unroll
      for (int k = 0; k < 16; ++k) {
        const float pear = (p[k] - sm4[k >> 2][k & 3] * syL[b_t][k])
                           * ix4[k >> 2][k & 3] * iyL[b_t][k];
        D[b_t][k * 512 + i] = bf_rne(ev[k] * inv - tanh_fast(pear));
      }
    }
    __syncthreads();

    // ===== phase 2: hatv + squash + y/vsum/stat update =====
    // wave w owns k = 2w, 2w+1. A = HT rows (k*64+dt*16+c), B cols 0-3 = D[b].
    for (int kk = 0; kk < 2; ++kk) {
      const int k = w * 2 + kk;
      f32x4 hacc[4];
      #pragma unroll
      for (int dt = 0; dt < 4; ++dt) hacc[dt] = f32x4{0.f, 0.f, 0.f, 0.f};
      #pragma unroll 4
      for (int it = 0; it < 16; ++it) {
        short8v Bf = {};
        if (c < 4) Bf = *(const short8v*)&D[c][k * 512 + it * 32 + g * 8];
        #pragma unroll
        for (int dt = 0; dt < 4; ++dt) {
          const short8v Af = *(const short8v*)
              &A.HTb[(size_t)(k * 64 + dt * 16 + c) * 512 + it * 32 + g * 8];
          hacc[dt] = MFMA(Af, Bf, hacc[dt], 0, 0, 0);
        }
      }
      // squash: lane (c,g) holds hv(b=c, k, d=dt*16+4g+j); sum d over g-lanes
      float sq = 0.f;
      #pragma unroll
      for (int dt = 0; dt < 4; ++dt)
        #pragma unroll
        for (int j = 0; j < 4; ++j) sq += hacc[dt][j] * hacc[dt][j];
      sq += __shfl_xor(sq, 16);
      sq += __shfl_xor(sq, 32);
      const float ss = (sq / (1.0f + sq)) * rsqrtf(sq + 1e-8f);

      if (round == 2) {
        if (c < 4) {
          #pragma unroll
          for (int dt = 0; dt < 4; ++dt)
            #pragma unroll
            for (int j = 0; j < 4; ++j)
              A.outp[(size_t)(b0 + c) * 1024 + k * 64 + dt * 16 + 4 * g + j] =
                  hacc[dt][j] * ss;
        }
      } else {
        float s1 = 0.f, s2 = 0.f;
        if (c < 4) {
          #pragma unroll
          for (int dt = 0; dt < 4; ++dt) {
            #pragma unroll
            for (int j = 0; j < 4; ++j) {
              const int idx = k * 64 + dt * 16 + 4 * g + j;
              const float v = hacc[dt][j] * ss;
              vL[c][idx] = bf_rne(bf_f(vL[c][idx]) + v);
              const float yn = (bf_f(yL[c][idx]) + v) * 0.5f;
              const ushort ynb = bf_rne(yn);
              yL[c][idx] = ynb;
              const float ynr = bf_f(ynb);
              s1 += ynr; s2 += ynr * ynr;
            }
          }
        }
        s1 += __shfl_xor(s1, 16);
        s1 += __shfl_xor(s1, 32);
        s2 += __shfl_xor(s2, 16);
        s2 += __shfl_xor(s2, 32);
        if (c < 4 && g == 0) {
          syL[c][k] = s1;
          iyL[c][k] = rsqrtf(s2 - s1 * s1 * (1.0f / 64.0f));
        }
      }
    }
    __syncthreads();
  }
}

// ===================== launch =====================
extern "C" void kernel_launch(void* const* d_in, const int* in_sizes, int n_in,
                              void* d_out, int out_size, void* d_ws, size_t ws_size,
                              hipStream_t stream) {
  char* w = (char*)d_ws;
  KArgs A;
  A.m  = (const float*)d_in[0];
  A.q  = (const float*)d_in[1];
  A.Ww = (const float*)d_in[2];
  A.Wb = (const float*)d_in[3];
  A.Hb     = (ushort*)(w + 0);         // 1048576
  A.HTb    = (ushort*)(w + 1048576);   // 1048576
  A.Yb0    = (ushort*)(w + 2097152);   // 262144
  A.smT    = (float*)(w + 2359296);    // 32768
  A.ixT    = (float*)(w + 2392064);    // 32768
  A.syT0   = (float*)(w + 2424832);    // 8192
  A.invyT0 = (float*)(w + 2433024);    // 8192
  A.outp = (float*)d_out;

  k_gemm<<<320, 256, 0, stream>>>(A);
  k_route<<<32, 512, 0, stream>>>(A);
}

// Round 11
// 118.465 us; speedup vs baseline: 3.0890x; 3.0890x over previous
//
#include <hip/hip_runtime.h>
#include <hip/hip_bf16.h>
#include <cstdint>
#include <cstddef>

#define IC 512     // in_caps
#define IDM 768    // in_dim
#define KC 16      // num_caps
#define NB 128     // batch
#define NOUT 1024  // KC*DC

typedef __attribute__((ext_vector_type(8))) short short8v;
typedef __attribute__((ext_vector_type(4))) float f32x4;

#define MFMA __builtin_amdgcn_mfma_f32_16x16x32_bf16

static __device__ __forceinline__ unsigned fbits(float x) {
  union { float f; unsigned u; } z; z.f = x; return z.u;
}
static __device__ __forceinline__ float bf_f(ushort u) {
  union { float f; unsigned u32; } z; z.u32 = ((unsigned)u) << 16; return z.f;
}
static __device__ __forceinline__ ushort bf_rne(float x) {
  __hip_bfloat16 h = __float2bfloat16(x);
  return *reinterpret_cast<ushort*>(&h);
}
// truncation hi/lo split (GEMM input path only)
static __device__ __forceinline__ void split2(float x, ushort& h, ushort& l) {
  h = (ushort)(fbits(x) >> 16);
  const float r = x - bf_f(h);
  l = (ushort)(fbits(r) >> 16);
}
static __device__ __forceinline__ void split8(const float* p, short8v& h, short8v& l) {
  const float4 x0 = *(const float4*)p;
  const float4 x1 = *(const float4*)(p + 4);
  const float xs[8] = {x0.x, x0.y, x0.z, x0.w, x1.x, x1.y, x1.z, x1.w};
  #pragma unroll
  for (int j = 0; j < 8; ++j) {
    ushort hh, ll; split2(xs[j], hh, ll);
    h[j] = (short)hh; l[j] = (short)ll;
  }
}
static __device__ __forceinline__ float tanh_fast(float x) {
  const float e2 = __expf(2.0f * x);
  return 1.0f - 2.0f / (e2 + 1.0f);
}

struct KArgs {
  const float *m, *q, *Ww, *Wb;
  ushort *Hb, *HTb;          // hat_m bf16 [i][n] and [n][i]
  ushort *Yb0, *Yb1, *Vb0;   // y round-0/1, vsum round-0 (bf16 [b][1024])
  float *pP;                 // p f32 [b][k*512+i] (slice-exclusive reuse)
  float *a1, *a2;            // a f32 [b][i*16+k]
  float *summT, *invxT;      // H row stats (sum, invnorm of bf16 H): [k][i]
  float *syT0, *invyT0;      // y0 stats: [k][b]
  float *outp;
};

// ===================== K1: GEMM (hi/lo f32-accurate) + bf16 epilogue ============
// Verbatim R9-verified kernel.
__global__ __launch_bounds__(256) void k_gemm(KArgs A)
{
  __shared__ float sred[2][2][32];
  const int t = threadIdx.x;
  const int bid = blockIdx.x;
  const int region = bid & 7, idx = bid >> 3;
  const int rt = (region & 1) * 10 + (idx % 10);
  const int nt = (region >> 1) * 4 + (idx / 10);
  const int w = t >> 6, L = t & 63, c = L & 15, g = L >> 4;
  const int wr = w >> 1, wc = w & 1;
  const int r0 = rt * 32, n0 = nt * 64;
  const int arow = r0 + wr * 16 + c;
  const int bcol = n0 + wc * 32 + c;
  const float* asrc = (arow < IC) ? (A.m + (size_t)arow * IDM)
                                  : (A.q + (size_t)(arow - IC) * IDM);
  const float* b0src = A.Ww + (size_t)bcol * IDM;
  const float* b1src = A.Ww + (size_t)(bcol + 16) * IDM;

  f32x4 acc0 = {}, acc1 = {};
  #pragma unroll 2
  for (int kb = 0; kb < IDM; kb += 32) {
    short8v ah, al, bh0, bl0, bh1, bl1;
    split8(asrc + kb + g * 8, ah, al);
    split8(b0src + kb + g * 8, bh0, bl0);
    split8(b1src + kb + g * 8, bh1, bl1);
    acc0 = MFMA(ah, bh0, acc0, 0, 0, 0);
    acc0 = MFMA(ah, bl0, acc0, 0, 0, 0);
    acc0 = MFMA(al, bh0, acc0, 0, 0, 0);
    acc1 = MFMA(ah, bh1, acc1, 0, 0, 0);
    acc1 = MFMA(ah, bl1, acc1, 0, 0, 0);
    acc1 = MFMA(al, bh1, acc1, 0, 0, 0);
  }

  const float bias0 = A.Wb[bcol];
  const float bias1 = A.Wb[bcol + 16];
  ushort h0[4], h1[4];
  float r0s[4], r1s[4];
  #pragma unroll
  for (int j = 0; j < 4; ++j) {
    h0[j] = bf_rne(acc0[j] + bias0); r0s[j] = bf_f(h0[j]);
    h1[j] = bf_rne(acc1[j] + bias1); r1s[j] = bf_f(h1[j]);
  }

  #pragma unroll
  for (int j = 0; j < 4; ++j) {
    float s = r0s[j] + r1s[j];
    float q2 = r0s[j] * r0s[j] + r1s[j] * r1s[j];
    #pragma unroll
    for (int off = 1; off < 16; off <<= 1) {
      s += __shfl_xor(s, off);
      q2 += __shfl_xor(q2, off);
    }
    if (c == 0) {
      sred[wc][0][wr * 16 + 4 * g + j] = s;
      sred[wc][1][wr * 16 + 4 * g + j] = q2;
    }
  }

  const int rowb = r0 + wr * 16 + 4 * g;
  if (rowb < IC) {
    #pragma unroll
    for (int j = 0; j < 4; ++j) {
      const size_t r = (size_t)(rowb + j) * NOUT;
      A.Hb[r + bcol] = h0[j];
      A.Hb[r + bcol + 16] = h1[j];
    }
    *(ushort4*)&A.HTb[(size_t)bcol * 512 + rowb] = make_ushort4(h0[0], h0[1], h0[2], h0[3]);
    *(ushort4*)&A.HTb[(size_t)(bcol + 16) * 512 + rowb] = make_ushort4(h1[0], h1[1], h1[2], h1[3]);
  } else {
    #pragma unroll
    for (int j = 0; j < 4; ++j) {
      const size_t r = (size_t)(rowb + j - IC) * NOUT;
      A.Yb0[r + bcol] = h0[j];
      A.Yb0[r + bcol + 16] = h1[j];
    }
  }
  __syncthreads();
  if (t < 32) {
    const int row = r0 + t;
    const float s = sred[0][0][t] + sred[1][0][t];
    const float q2 = sred[0][1][t] + sred[1][1][t];
    const float inv = rsqrtf(q2 - s * s * (1.0f / 64.0f));
    if (row < IC) {
      A.summT[nt * 512 + row] = s;
      A.invxT[nt * 512 + row] = inv;
    } else {
      A.syT0[nt * 128 + (row - IC)] = s;
      A.invyT0[nt * 128 + (row - IC)] = inv;
    }
  }
}

// ===================== K2: fused round kernel =====================
// Block (k = bid>>3, b-tile = bid&7 -> XCD), 256 thr (4 waves).
// R=0: corr0 (MFMA, d=1/16) -> D(LDS) -> hatv0 -> y1/v0 (global) -> P1,a1.
// R=1: softmax(a1)+p1 -> D -> hatv1 -> y2,vsum (LDS) -> p2,a2.
// R=2: softmax(a2)+p2 -> D -> hatv2 -> squash -> outp.
template <int R>
__global__ __launch_bounds__(256) void k_round(KArgs A)
{
  __shared__ ushort D[16][520];     // [b][i] bf16, +8 pad
  __shared__ ushort yL[16][72];     // y_new k-slice [b][d]
  __shared__ ushort vL[16][72];     // vsum_new k-slice
  __shared__ float red[3][4][16];
  __shared__ float sscale[16], syL[16], iyL[16];

  const int t = threadIdx.x;
  const int k = blockIdx.x >> 3, bt = blockIdx.x & 7;
  const int b0 = bt * 16;
  const int w = t >> 6, L = t & 63, c = L & 15, g = L >> 4;

  // ---------- phase A: D into LDS ----------
  if (R == 0) {
    // P0[i][b] = H . y0 per i-tile; C layout: col(c)=b, row(4g+j)=i  [R9-verified]
    const float syb = A.syT0[k * 128 + b0 + c] * (1.0f / 64.0f);
    const float iyb = A.invyT0[k * 128 + b0 + c];
    #pragma unroll 2
    for (int n = 0; n < 8; ++n) {
      const int i0 = (w * 8 + n) * 16;
      f32x4 P = {};
      #pragma unroll
      for (int ks = 0; ks < 2; ++ks) {
        const short8v Af = *(const short8v*)
            &A.Hb[(size_t)(i0 + c) * 1024 + k * 64 + ks * 32 + g * 8];
        const short8v Bf = *(const short8v*)
            &A.Yb0[(size_t)(b0 + c) * 1024 + k * 64 + ks * 32 + g * 8];
        P = MFMA(Af, Bf, P, 0, 0, 0);
      }
      const f32x4 sm4 = *(const f32x4*)&A.summT[(size_t)k * 512 + i0 + 4 * g];
      const f32x4 ix4 = *(const f32x4*)&A.invxT[(size_t)k * 512 + i0 + 4 * g];
      ushort4 dv;
      dv.x = bf_rne(0.0625f - tanh_fast((P[0] - sm4[0] * syb) * ix4[0] * iyb));
      dv.y = bf_rne(0.0625f - tanh_fast((P[1] - sm4[1] * syb) * ix4[1] * iyb));
      dv.z = bf_rne(0.0625f - tanh_fast((P[2] - sm4[2] * syb) * ix4[2] * iyb));
      dv.w = bf_rne(0.0625f - tanh_fast((P[3] - sm4[3] * syb) * ix4[3] * iyb));
      *(ushort4*)&D[c][i0 + 4 * g] = dv;
    }
  } else {
    // softmax over k per (b,i); keep own-k d; D = d - p
    const int b = t >> 4, io = t & 15;
    const float* ar = (R == 1 ? A.a1 : A.a2) + (size_t)(b0 + b) * 8192;
    const float* pr = A.pP + (size_t)(b0 + b) * 8192 + (size_t)k * 512;
    for (int ii = 0; ii < 32; ++ii) {
      const int i = ii * 16 + io;
      float av[16];
      float mx = -1e30f;
      #pragma unroll
      for (int m4 = 0; m4 < 4; ++m4) {
        const f32x4 a4 = *(const f32x4*)&ar[(size_t)i * 16 + m4 * 4];
        #pragma unroll
        for (int j = 0; j < 4; ++j) {
          av[m4 * 4 + j] = a4[j];
          mx = fmaxf(mx, a4[j]);
        }
      }
      float es = 0.f;
      #pragma unroll
      for (int kk = 0; kk < 16; ++kk) { av[kk] = __expf(av[kk] - mx); es += av[kk]; }
      D[b][i] = bf_rne(av[k] / es - pr[i]);
    }
  }
  __syncthreads();

  // ---------- phase B: hatv + squash ----------
  // A = D (rows b via lane c), B = HT (rows d); C: col(c)=d, row(4g+j)=b  [R9-verified]
  f32x4 hacc = {};
  #pragma unroll 4
  for (int it = 0; it < 16; ++it) {
    const short8v Af = *(const short8v*)&D[c][it * 32 + g * 8];
    const short8v Bf = *(const short8v*)
        &A.HTb[(size_t)(k * 64 + w * 16 + c) * 512 + it * 32 + g * 8];
    hacc = MFMA(Af, Bf, hacc, 0, 0, 0);
  }
  float sq[4];
  #pragma unroll
  for (int j = 0; j < 4; ++j) {
    sq[j] = hacc[j] * hacc[j];
    #pragma unroll
    for (int off = 1; off < 16; off <<= 1) sq[j] += __shfl_xor(sq[j], off);
  }
  if (c == 0) {
    #pragma unroll
    for (int j = 0; j < 4; ++j) red[0][w][4 * g + j] = sq[j];
  }
  __syncthreads();
  if (t < 16) {
    const float s = red[0][0][t] + red[0][1][t] + red[0][2][t] + red[0][3][t];
    sscale[t] = (s / (1.0f + s)) * rsqrtf(s + 1e-8f);
  }
  __syncthreads();

  const int d = w * 16 + c;
  if (R == 2) {
    #pragma unroll
    for (int j = 0; j < 4; ++j)
      A.outp[(size_t)(b0 + 4 * g + j) * 1024 + k * 64 + d] = hacc[j] * sscale[4 * g + j];
  } else {
    // ---------- updates: vsum, y, stats ----------
    float s1[4], s2[4];
    #pragma unroll
    for (int j = 0; j < 4; ++j) {
      const int b = 4 * g + j;
      const size_t gi = (size_t)(b0 + b) * 1024 + (size_t)k * 64 + d;
      const float v = hacc[j] * sscale[b];
      const float vs = (R == 0) ? v : (bf_f(A.Vb0[gi]) + v);
      const ushort vsb = bf_rne(vs);
      const float yo = bf_f((R == 0 ? A.Yb0 : A.Yb1)[gi]);
      const ushort ynb = bf_rne((yo + v) * 0.5f);
      if (R == 0) { A.Vb0[gi] = vsb; A.Yb1[gi] = ynb; }
      vL[b][d] = vsb;
      yL[b][d] = ynb;
      const float ynr = bf_f(ynb);
      s1[j] = ynr; s2[j] = ynr * ynr;
    }
    #pragma unroll
    for (int j = 0; j < 4; ++j) {
      #pragma unroll
      for (int off = 1; off < 16; off <<= 1) {
        s1[j] += __shfl_xor(s1[j], off);
        s2[j] += __shfl_xor(s2[j], off);
      }
    }
    if (c == 0) {
      #pragma unroll
      for (int j = 0; j < 4; ++j) {
        red[1][w][4 * g + j] = s1[j];
        red[2][w][4 * g + j] = s2[j];
      }
    }
    __syncthreads();
    if (t < 16) {
      const float s = red[1][0][t] + red[1][1][t] + red[1][2][t] + red[1][3][t];
      const float q2 = red[2][0][t] + red[2][1][t] + red[2][2][t] + red[2][3][t];
      syL[t] = s;
      iyL[t] = rsqrtf(q2 - s * s * (1.0f / 64.0f));
    }
    __syncthreads();

    // ---------- phase C: next round's P (tanh'd) and a ----------
    const float syb = syL[c] * (1.0f / 64.0f);
    const float iyb = iyL[c];
    float* aw = (R == 0 ? A.a1 : A.a2) + (size_t)(b0 + c) * 8192;
    #pragma unroll 2
    for (int n = 0; n < 8; ++n) {
      const int i0 = (w * 8 + n) * 16;
      f32x4 P = {}, Aa = {};
      #pragma unroll
      for (int ks = 0; ks < 2; ++ks) {
        const short8v Af = *(const short8v*)
            &A.Hb[(size_t)(i0 + c) * 1024 + k * 64 + ks * 32 + g * 8];
        const short8v By = *(const short8v*)&yL[c][ks * 32 + g * 8];
        const short8v Bv = *(const short8v*)&vL[c][ks * 32 + g * 8];
        P = MFMA(Af, By, P, 0, 0, 0);
        Aa = MFMA(Af, Bv, Aa, 0, 0, 0);
      }
      const f32x4 sm4 = *(const f32x4*)&A.summT[(size_t)k * 512 + i0 + 4 * g];
      const f32x4 ix4 = *(const f32x4*)&A.invxT[(size_t)k * 512 + i0 + 4 * g];
      f32x4 p4;
      #pragma unroll
      for (int j = 0; j < 4; ++j)
        p4[j] = tanh_fast((P[j] - sm4[j] * syb) * ix4[j] * iyb);
      *(f32x4*)&A.pP[(size_t)(b0 + c) * 8192 + (size_t)k * 512 + i0 + 4 * g] = p4;
      #pragma unroll
      for (int j = 0; j < 4; ++j)
        aw[(size_t)(i0 + 4 * g + j) * 16 + k] = Aa[j];
    }
  }
}

// ===================== launch =====================
extern "C" void kernel_launch(void* const* d_in, const int* in_sizes, int n_in,
                              void* d_out, int out_size, void* d_ws, size_t ws_size,
                              hipStream_t stream) {
  char* w = (char*)d_ws;
  KArgs A;
  A.m  = (const float*)d_in[0];
  A.q  = (const float*)d_in[1];
  A.Ww = (const float*)d_in[2];
  A.Wb = (const float*)d_in[3];
  A.Hb     = (ushort*)(w + 0);          // 1048576
  A.HTb    = (ushort*)(w + 1048576);    // 1048576
  A.Yb0    = (ushort*)(w + 2097152);    // 262144
  A.Yb1    = (ushort*)(w + 2359296);    // 262144
  A.Vb0    = (ushort*)(w + 2621440);    // 262144
  A.pP     = (float*)(w + 2883584);     // 4194304
  A.a1     = (float*)(w + 7077888);     // 4194304
  A.a2     = (float*)(w + 11272192);    // 4194304
  A.summT  = (float*)(w + 15466496);    // 32768
  A.invxT  = (float*)(w + 15499264);    // 32768
  A.syT0   = (float*)(w + 15532032);    // 8192
  A.invyT0 = (float*)(w + 15540224);    // 8192
  A.outp = (float*)d_out;

  k_gemm<<<320, 256, 0, stream>>>(A);
  k_round<0><<<128, 256, 0, stream>>>(A);
  k_round<1><<<128, 256, 0, stream>>>(A);
  k_round<2><<<128, 256, 0, stream>>>(A);
}